// Round 10
// baseline (456.771 us; speedup 1.0000x reference)
//
#include <hip/hip_runtime.h>
#include <hip/hip_bf16.h>
#include <cstdint>
#include <cstddef>

#define NN 50000
#define NE 600000
#define NG 2000
#define NBUCK 49          // ceil(50000 / 1024)
#define SLOTS 16
#define NCHUNK 3125       // 50000 / 16 exactly

typedef __attribute__((ext_vector_type(8))) short bf8;
typedef __attribute__((ext_vector_type(4))) float f32x4;

__device__ __forceinline__ unsigned short f2bf(float f) {
    uint32_t u = __float_as_uint(f);
    uint32_t r = (u + 0x7FFFu + ((u >> 16) & 1u)) >> 16;
    return (unsigned short)r;
}
__device__ __forceinline__ float bf2f(unsigned short h) {
    return __uint_as_float(((uint32_t)h) << 16);
}
__device__ __forceinline__ float lo16(uint32_t v) { return __uint_as_float(v << 16); }
__device__ __forceinline__ float hi16(uint32_t v) { return __uint_as_float(v & 0xFFFF0000u); }

// ---------------- Fused preamble: conv + pack_w x2 + stat/bucket zeroing ----------------
// Flat grid, block-range dispatch:
//   [0, 6250)        conv fp32->bf16 (2 graphs x 3125 blocks)
//   [6250, 6258)     pack W1 (64x128), 2 graphs x 4 blocks
//   [6258, 6266)     pack W2 (128x64), 2 graphs x 4 blocks
//   [6266, 6315)     zero sums1/sums2/hsums (12416 words)
//   6315             zero bucketCnt (98 ints)
#define PREP_CONV 6250
#define PREP_P1   6258
#define PREP_P2   6266
#define PREP_ZS   6315
#define PREP_TOT  6316

__device__ __forceinline__ void pack_w_body(const float* __restrict__ W,
                                            unsigned short* __restrict__ o,
                                            int idx, int K, int N) {
    const int total = (N / 16) * (K / 32) * 64;
    if (idx >= total) return;
    int l = idx & 63;
    int th = idx >> 6;
    int h = th % (K / 32);
    int t = th / (K / 32);
    int col = t * 16 + (l & 15);
    int k0 = h * 32 + (l >> 4) * 8;
    ushort4 lo = make_ushort4(f2bf(W[(k0 + 0) * N + col]), f2bf(W[(k0 + 1) * N + col]),
                              f2bf(W[(k0 + 2) * N + col]), f2bf(W[(k0 + 3) * N + col]));
    ushort4 hi = make_ushort4(f2bf(W[(k0 + 4) * N + col]), f2bf(W[(k0 + 5) * N + col]),
                              f2bf(W[(k0 + 6) * N + col]), f2bf(W[(k0 + 7) * N + col]));
    *(ushort4*)&o[idx * 8] = lo;
    *(ushort4*)&o[idx * 8 + 4] = hi;
}

__global__ __launch_bounds__(256) void prep_kernel(const float* __restrict__ x0,
                                                   const float* __restrict__ x1,
                                                   unsigned short* __restrict__ xbf,
                                                   const float* __restrict__ W1c,
                                                   const float* __restrict__ W1s,
                                                   unsigned short* __restrict__ Wp1,
                                                   const float* __restrict__ W2c,
                                                   const float* __restrict__ W2s,
                                                   unsigned short* __restrict__ Wp2,
                                                   float* __restrict__ sums,
                                                   int* __restrict__ bucketCnt) {
    const int bid = blockIdx.x;
    const int tid = threadIdx.x;
    if (bid < PREP_CONV) {
        const int b = bid >= 3125;
        const int lb = b ? bid - 3125 : bid;
        const float* x = b ? x1 : x0;
        unsigned short* o = xbf + (size_t)b * NN * 64;
        int i = (lb * 256 + tid) * 4;
        if (i + 3 < NN * 64) {
            float4 v = *(const float4*)&x[i];
            *(ushort4*)&o[i] = make_ushort4(f2bf(v.x), f2bf(v.y), f2bf(v.z), f2bf(v.w));
        }
    } else if (bid < PREP_P1) {
        const int local = bid - PREP_CONV;
        const int b = local >> 2;
        pack_w_body(b ? W1s : W1c, Wp1 + (size_t)b * 64 * 128,
                    (local & 3) * 256 + tid, 64, 128);
    } else if (bid < PREP_P2) {
        const int local = bid - PREP_P1;
        const int b = local >> 2;
        pack_w_body(b ? W2s : W2c, Wp2 + (size_t)b * 128 * 64,
                    (local & 3) * 256 + tid, 128, 64);
    } else if (bid < PREP_ZS) {
        int i = (bid - PREP_P2) * 256 + tid;
        if (i < 12416) sums[i] = 0.f;
    } else {
        if (tid < 2 * NBUCK) bucketCnt[tid] = 0;
    }
}

// ---------------- Bucketed CSR build ----------------
__global__ __launch_bounds__(256) void bucket_hist(const int* __restrict__ d0,
                                                   const int* __restrict__ d1,
                                                   int* __restrict__ bucketCnt, int nE) {
    int b = blockIdx.y;
    const int* dst = b ? d1 : d0;
    __shared__ int h[NBUCK];
    for (int i = threadIdx.x; i < NBUCK; i += 256) h[i] = 0;
    __syncthreads();
    for (int e = blockIdx.x * 256 + threadIdx.x; e < nE; e += gridDim.x * 256)
        atomicAdd(&h[dst[e] >> 10], 1);
    __syncthreads();
    for (int i = threadIdx.x; i < NBUCK; i += 256)
        if (h[i]) atomicAdd(&bucketCnt[b * NBUCK + i], h[i]);
}

__global__ void bucket_scan(const int* __restrict__ bucketCnt,
                            int* __restrict__ bucketOff, int* __restrict__ bucketCur) {
    int b = threadIdx.x;
    if (b < 2) {
        int run = 0;
        for (int i = 0; i < NBUCK; ++i) {
            bucketOff[b * NBUCK + i] = run;
            bucketCur[b * NBUCK + i] = run;
            run += bucketCnt[b * NBUCK + i];
        }
    }
}

__global__ __launch_bounds__(256) void bucket_scatter(const int* __restrict__ s0,
                                                      const int* __restrict__ d0,
                                                      const int* __restrict__ s1,
                                                      const int* __restrict__ d1,
                                                      int* __restrict__ bucketCur,
                                                      uint32_t* __restrict__ bent, int nE) {
    int b = blockIdx.y;
    const int* src = b ? s1 : s0;
    const int* dst = b ? d1 : d0;
    __shared__ int cnt[NBUCK];
    __shared__ int base[NBUCK];
    const int tid = threadIdx.x;
    for (int i = tid; i < NBUCK; i += 256) cnt[i] = 0;
    __syncthreads();

    const int e0 = blockIdx.x * 2048 + tid;
    int bk[8], slot[8];
    uint32_t pay[8];
#pragma unroll
    for (int k = 0; k < 8; ++k) {
        int e = e0 + k * 256;
        if (e < nE) {
            int d = dst[e], s = src[e];
            bk[k] = d >> 10;
            pay[k] = ((uint32_t)(d & 1023) << 16) | (uint32_t)s;
            slot[k] = atomicAdd(&cnt[bk[k]], 1);
        } else bk[k] = -1;
    }
    __syncthreads();
    for (int i = tid; i < NBUCK; i += 256) {
        int c = cnt[i];
        base[i] = c ? atomicAdd(&bucketCur[b * NBUCK + i], c) : 0;
    }
    __syncthreads();
#pragma unroll
    for (int k = 0; k < 8; ++k)
        if (bk[k] >= 0)
            bent[(size_t)b * NE + base[bk[k]] + slot[k]] = pay[k];
}

__global__ __launch_bounds__(256) void csr_build(const uint32_t* __restrict__ bent,
                                                 const int* __restrict__ bucketOff,
                                                 const int* __restrict__ bucketCnt,
                                                 int* __restrict__ row_ptr,
                                                 float* __restrict__ dinv,
                                                 uint16_t* __restrict__ perm) {
    __shared__ int lcnt[1024];
    __shared__ int lcur[1024];
    __shared__ int sscan[256];
    const int bk = blockIdx.x;
    const int b = blockIdx.y;
    const int tid = threadIdx.x;
    const int ebase = bucketOff[b * NBUCK + bk];
    const int ecnt = bucketCnt[b * NBUCK + bk];
    const int node0 = bk << 10;
    const uint32_t* be = bent + (size_t)b * NE + ebase;
    int* rp = row_ptr + b * (NN + 1);
    float* dv = dinv + (size_t)b * NN;
    uint16_t* pm = perm + (size_t)b * NE + ebase;

    for (int i = tid; i < 1024; i += 256) lcnt[i] = 0;
    __syncthreads();
    for (int i = tid; i < ecnt; i += 256) atomicAdd(&lcnt[be[i] >> 16], 1);
    __syncthreads();

    int c[4], s = 0;
#pragma unroll
    for (int j = 0; j < 4; ++j) { c[j] = lcnt[tid * 4 + j]; s += c[j]; }
    sscan[tid] = s;
    __syncthreads();
    for (int off = 1; off < 256; off <<= 1) {
        int v = (tid >= off) ? sscan[tid - off] : 0;
        __syncthreads();
        sscan[tid] += v;
        __syncthreads();
    }
    int run = sscan[tid] - s;
#pragma unroll
    for (int j = 0; j < 4; ++j) {
        int nl = tid * 4 + j;
        int g = node0 + nl;
        if (g < NN) {
            rp[g] = ebase + run;
            lcur[nl] = run;
            dv[g] = rsqrtf((float)c[j] + 1.0f);
        }
        run += c[j];
    }
    if (bk == NBUCK - 1 && tid == 0) rp[NN] = ebase + ecnt;
    __syncthreads();

    for (int i = tid; i < ecnt; i += 256) {
        uint32_t en = be[i];
        int nl = en >> 16;
        int pos = atomicAdd(&lcur[nl], 1);
        pm[pos] = (uint16_t)(en & 0xFFFFu);
    }
}

__global__ __launch_bounds__(256) void weight_fill(const uint16_t* __restrict__ perm,
                                                   const float* __restrict__ dinv,
                                                   uint32_t* __restrict__ permw, int nE) {
    int b = blockIdx.y;
    const uint16_t* pm = perm + (size_t)b * NE;
    const float* dv = dinv + (size_t)b * NN;
    uint32_t* pw = permw + (size_t)b * NE;
    int i = (blockIdx.x * 256 + threadIdx.x) * 4;
    if (i + 3 < nE) {
        ushort4 s4 = *(const ushort4*)&pm[i];
        uint4 o;
        o.x = ((uint32_t)f2bf(dv[s4.x]) << 16) | (uint32_t)s4.x;
        o.y = ((uint32_t)f2bf(dv[s4.y]) << 16) | (uint32_t)s4.y;
        o.z = ((uint32_t)f2bf(dv[s4.z]) << 16) | (uint32_t)s4.z;
        o.w = ((uint32_t)f2bf(dv[s4.w]) << 16) | (uint32_t)s4.w;
        *(uint4*)&pw[i] = o;
    } else {
        for (; i < nE; ++i) {
            uint16_t s = pm[i];
            pw[i] = ((uint32_t)f2bf(dv[s]) << 16) | (uint32_t)s;
        }
    }
}

// ---------------- GEMM1 (MFMA, swapped operands) + fused BN1 stats ----------------
// Y[n,128] = X[n,64] @ W[64,128]. Stats computed from f32 acc (pre-bf16-round) via
// staggered LDS atomics: lane m processes t-block (tt+m)&7 so the 64 lanes of a wave
// hit 64 DISTINCT ls[] addresses per step (conflict-free). One global flush per block.
__global__ __launch_bounds__(256) void gemm1_mfma(const unsigned short* __restrict__ Xbf,
                                                  const unsigned short* __restrict__ Wp,
                                                  unsigned short* __restrict__ Y,
                                                  float* __restrict__ sums) {
    __shared__ float ls[128], lq[128];
    const int b = blockIdx.y;
    const unsigned short* __restrict__ X = Xbf + (size_t)b * NN * 64;
    const unsigned short* __restrict__ W = Wp + (size_t)b * 64 * 128;
    unsigned short* __restrict__ Yb = Y + (size_t)b * NN * 128;
    const int tid = threadIdx.x;
    const int w = tid >> 6, lane = tid & 63;
    const int chunk = blockIdx.x * 4 + w;
    const bool act = chunk < NCHUNK;
    const int m = lane & 15, quad = lane >> 4;

    if (tid < 128) { ls[tid] = 0.f; lq[tid] = 0.f; }
    __syncthreads();

    if (act) {
        const int row = chunk * 16 + m;
        bf8 a0 = *(const bf8*)&X[(size_t)row * 64 + quad * 8];
        bf8 a1 = *(const bf8*)&X[(size_t)row * 64 + 32 + quad * 8];
        f32x4 acc[8];
#pragma unroll
        for (int t = 0; t < 8; ++t) acc[t] = (f32x4){0.f, 0.f, 0.f, 0.f};
#pragma unroll
        for (int t = 0; t < 8; ++t) {
            bf8 b0 = *(const bf8*)&W[((t * 2 + 0) * 64 + lane) * 8];
            bf8 b1 = *(const bf8*)&W[((t * 2 + 1) * 64 + lane) * 8];
            acc[t] = __builtin_amdgcn_mfma_f32_16x16x32_bf16(b0, a0, acc[t], 0, 0, 0);
            acc[t] = __builtin_amdgcn_mfma_f32_16x16x32_bf16(b1, a1, acc[t], 0, 0, 0);
        }
#pragma unroll
        for (int t = 0; t < 8; ++t) {
            uint32_t lo = (uint32_t)f2bf(acc[t][0]) | ((uint32_t)f2bf(acc[t][1]) << 16);
            uint32_t hi = (uint32_t)f2bf(acc[t][2]) | ((uint32_t)f2bf(acc[t][3]) << 16);
            *(uint2*)&Yb[(size_t)row * 128 + t * 16 + quad * 4] = make_uint2(lo, hi);
        }
        // stats: staggered per-lane LDS accumulation (conflict-free within wave)
#pragma unroll
        for (int tt = 0; tt < 8; ++tt) {
            const int t = (tt + m) & 7;
            const int ch = t * 16 + quad * 4;
#pragma unroll
            for (int r = 0; r < 4; ++r) {
                const float v = acc[t][r];
                atomicAdd(&ls[ch + r], v);
                atomicAdd(&lq[ch + r], v * v);
            }
        }
    }
    __syncthreads();
    if (tid < 128) {
        int slot = blockIdx.x & (SLOTS - 1);
        float* sb = sums + (size_t)(b * SLOTS + slot) * 256;
        atomicAdd(&sb[tid], ls[tid]);
        atomicAdd(&sb[128 + tid], lq[tid]);
    }
}

// ---------------- GEMM2 (MFMA, swapped operands, fused BN-finalize prologue) ----------------
__global__ __launch_bounds__(256) void gemm2_mfma(const unsigned short* __restrict__ H1,
                                                  const unsigned short* __restrict__ Wp,
                                                  const float* __restrict__ sums,
                                                  const float* __restrict__ g0,
                                                  const float* __restrict__ g1,
                                                  const float* __restrict__ be0,
                                                  const float* __restrict__ be1,
                                                  unsigned short* __restrict__ Y) {
    __shared__ float scLds[128], shLds[128];
    const int b = blockIdx.y;
    const unsigned short* __restrict__ X = H1 + (size_t)b * NN * 128;
    const unsigned short* __restrict__ W = Wp + (size_t)b * 128 * 64;
    unsigned short* __restrict__ Yb = Y + (size_t)b * NN * 64;
    const int tid = threadIdx.x;

    if (tid < 128) {
        float s = 0.f, s2 = 0.f;
#pragma unroll
        for (int k = 0; k < SLOTS; ++k) {
            const float* sb = sums + (size_t)(b * SLOTS + k) * 256;
            s += sb[tid];
            s2 += sb[128 + tid];
        }
        const float invN = 1.0f / (float)NN;
        float mean = s * invN;
        float var = s2 * invN - mean * mean;
        float gamma = b ? g1[tid] : g0[tid];
        float beta = b ? be1[tid] : be0[tid];
        float sc = gamma * rsqrtf(var + 1e-5f);
        scLds[tid] = sc;
        shLds[tid] = beta - mean * sc;
    }
    __syncthreads();

    const int w = tid >> 6, lane = tid & 63;
    const int chunk = blockIdx.x * 4 + w;
    if (chunk >= NCHUNK) return;
    const int m = lane & 15, quad = lane >> 4;
    const int row = chunk * 16 + m;

    f32x4 acc[4];
#pragma unroll
    for (int t = 0; t < 4; ++t) acc[t] = (f32x4){0.f, 0.f, 0.f, 0.f};
#pragma unroll
    for (int h = 0; h < 4; ++h) {
        const int k0 = h * 32 + quad * 8;
        bf8 araw = *(const bf8*)&X[(size_t)row * 128 + k0];
        float4 sc0 = *(const float4*)&scLds[k0];
        float4 sc1 = *(const float4*)&scLds[k0 + 4];
        float4 sh0 = *(const float4*)&shLds[k0];
        float4 sh1 = *(const float4*)&shLds[k0 + 4];
        float scv[8] = {sc0.x, sc0.y, sc0.z, sc0.w, sc1.x, sc1.y, sc1.z, sc1.w};
        float shv[8] = {sh0.x, sh0.y, sh0.z, sh0.w, sh1.x, sh1.y, sh1.z, sh1.w};
        bf8 af;
#pragma unroll
        for (int j = 0; j < 8; ++j) {
            float v = bf2f((unsigned short)araw[j]);
            v = fmaxf(fmaf(v, scv[j], shv[j]), 0.f);
            af[j] = (short)f2bf(v);
        }
#pragma unroll
        for (int t = 0; t < 4; ++t) {
            bf8 bf = *(const bf8*)&W[((t * 4 + h) * 64 + lane) * 8];
            acc[t] = __builtin_amdgcn_mfma_f32_16x16x32_bf16(bf, af, acc[t], 0, 0, 0);
        }
    }
#pragma unroll
    for (int t = 0; t < 4; ++t) {
        uint32_t lo = (uint32_t)f2bf(acc[t][0]) | ((uint32_t)f2bf(acc[t][1]) << 16);
        uint32_t hi = (uint32_t)f2bf(acc[t][2]) | ((uint32_t)f2bf(acc[t][3]) << 16);
        *(uint2*)&Yb[(size_t)row * 64 + t * 16 + quad * 4] = make_uint2(lo, hi);
    }
}

// ---------------- Batched aggregation: 2 nodes per wave, XCD-partitioned grid ----------------
template<bool STATS>
__global__ __launch_bounds__(256) void agg2_kernel(const unsigned short* __restrict__ hall,
                                                   const int* __restrict__ row_ptr,
                                                   const uint32_t* __restrict__ permw,
                                                   const float* __restrict__ dinv,
                                                   unsigned short* __restrict__ out,
                                                   float* __restrict__ sums, int nNodes) {
    const int bid = blockIdx.x;
    const int xcd = bid & 7;
    const int b = xcd >> 2;                      // graph = XCD group
    const int j = (bid >> 3) * 4 + (xcd & 3);    // block index within graph
    const unsigned short* __restrict__ h = hall + (size_t)b * NN * 64;
    const int* rp = row_ptr + b * (NN + 1);
    const uint32_t* pe = permw + (size_t)b * NE;
    const float* dv = dinv + (size_t)b * NN;
    unsigned short* ob = out + (size_t)b * nNodes * 64;

    const int w = threadIdx.x >> 6;
    const int lane = threadIdx.x & 63;
    const int q = lane & 15;        // channel quad: channels q*4 .. q*4+3
    const int r = lane >> 4;        // edge sub-slot 0..3 within each batch step
    const int d0 = j * 8 + w * 2;
    const int d1 = d0 + 1;
    const bool actA = d0 < nNodes;
    const bool actB = d1 < nNodes;

    float fA0 = 0.f, fA1 = 0.f, fA2 = 0.f, fA3 = 0.f;
    float fB0 = 0.f, fB1 = 0.f, fB2 = 0.f, fB3 = 0.f;
    int p0a = 0, p1a = 0, p0b = 0, p1b = 0;
    float dia = 0.f, dib = 0.f;
    if (actA) { p0a = rp[d0]; p1a = rp[d0 + 1]; dia = dv[d0]; }
    if (actB) { p0b = rp[d1]; p1b = rp[d1 + 1]; dib = dv[d1]; }

    float aA0 = 0.f, aA1 = 0.f, aA2 = 0.f, aA3 = 0.f;
    float aB0 = 0.f, aB1 = 0.f, aB2 = 0.f, aB3 = 0.f;
    int pa = p0a, pb = p0b;
    while (pa < p1a || pb < p1b) {
        uint32_t enA[4], enB[4];
#pragma unroll
        for (int k = 0; k < 4; ++k) {
            int e = pa + k * 4 + r;
            bool vld = e < p1a;
            enA[k] = pe[vld ? e : p0a];
            if (!vld) enA[k] &= 0xFFFFu;          // zero weight, warm row idx
        }
#pragma unroll
        for (int k = 0; k < 4; ++k) {
            int e = pb + k * 4 + r;
            bool vld = e < p1b;
            enB[k] = pe[vld ? e : p0b];
            if (!vld) enB[k] &= 0xFFFFu;
        }
#pragma unroll
        for (int k = 0; k < 4; ++k) {
            const int idx = (int)(enA[k] & 0xFFFFu);
            const float wk = __uint_as_float(enA[k] & 0xFFFF0000u);
            const uint2 hv = *(const uint2*)&h[(size_t)idx * 64 + q * 4];
            aA0 = fmaf(wk, lo16(hv.x), aA0);
            aA1 = fmaf(wk, hi16(hv.x), aA1);
            aA2 = fmaf(wk, lo16(hv.y), aA2);
            aA3 = fmaf(wk, hi16(hv.y), aA3);
        }
#pragma unroll
        for (int k = 0; k < 4; ++k) {
            const int idx = (int)(enB[k] & 0xFFFFu);
            const float wk = __uint_as_float(enB[k] & 0xFFFF0000u);
            const uint2 hv = *(const uint2*)&h[(size_t)idx * 64 + q * 4];
            aB0 = fmaf(wk, lo16(hv.x), aB0);
            aB1 = fmaf(wk, hi16(hv.x), aB1);
            aB2 = fmaf(wk, lo16(hv.y), aB2);
            aB3 = fmaf(wk, hi16(hv.y), aB3);
        }
        pa += 16;
        pb += 16;
    }
    aA0 += __shfl_xor(aA0, 16, 64); aA0 += __shfl_xor(aA0, 32, 64);
    aA1 += __shfl_xor(aA1, 16, 64); aA1 += __shfl_xor(aA1, 32, 64);
    aA2 += __shfl_xor(aA2, 16, 64); aA2 += __shfl_xor(aA2, 32, 64);
    aA3 += __shfl_xor(aA3, 16, 64); aA3 += __shfl_xor(aA3, 32, 64);
    aB0 += __shfl_xor(aB0, 16, 64); aB0 += __shfl_xor(aB0, 32, 64);
    aB1 += __shfl_xor(aB1, 16, 64); aB1 += __shfl_xor(aB1, 32, 64);
    aB2 += __shfl_xor(aB2, 16, 64); aB2 += __shfl_xor(aB2, 32, 64);
    aB3 += __shfl_xor(aB3, 16, 64); aB3 += __shfl_xor(aB3, 32, 64);

    if (actA) {
        const uint2 sv = *(const uint2*)&h[(size_t)d0 * 64 + q * 4];
        fA0 = dia * fmaf(dia, lo16(sv.x), aA0);
        fA1 = dia * fmaf(dia, hi16(sv.x), aA1);
        fA2 = dia * fmaf(dia, lo16(sv.y), aA2);
        fA3 = dia * fmaf(dia, hi16(sv.y), aA3);
        if (r == 0) {
            uint32_t o0 = (uint32_t)f2bf(fA0) | ((uint32_t)f2bf(fA1) << 16);
            uint32_t o1 = (uint32_t)f2bf(fA2) | ((uint32_t)f2bf(fA3) << 16);
            *(uint2*)&ob[(size_t)d0 * 64 + q * 4] = make_uint2(o0, o1);
        }
    }
    if (actB) {
        const uint2 sv = *(const uint2*)&h[(size_t)d1 * 64 + q * 4];
        fB0 = dib * fmaf(dib, lo16(sv.x), aB0);
        fB1 = dib * fmaf(dib, hi16(sv.x), aB1);
        fB2 = dib * fmaf(dib, lo16(sv.y), aB2);
        fB3 = dib * fmaf(dib, hi16(sv.y), aB3);
        if (r == 0) {
            uint32_t o0 = (uint32_t)f2bf(fB0) | ((uint32_t)f2bf(fB1) << 16);
            uint32_t o1 = (uint32_t)f2bf(fB2) | ((uint32_t)f2bf(fB3) << 16);
            *(uint2*)&ob[(size_t)d1 * 64 + q * 4] = make_uint2(o0, o1);
        }
    }
    if constexpr (STATS) {
        __shared__ float ls[256], ls2[256];
        if (lane < 16) {
            *(float4*)&ls[w * 64 + q * 4] =
                make_float4(fA0 + fB0, fA1 + fB1, fA2 + fB2, fA3 + fB3);
            *(float4*)&ls2[w * 64 + q * 4] =
                make_float4(fA0 * fA0 + fB0 * fB0, fA1 * fA1 + fB1 * fB1,
                            fA2 * fA2 + fB2 * fB2, fA3 * fA3 + fB3 * fB3);
        }
        __syncthreads();
        if (threadIdx.x < 64) {
            const int t = threadIdx.x;
            float s  = ls[t]  + ls[t + 64]  + ls[t + 128]  + ls[t + 192];
            float s2 = ls2[t] + ls2[t + 64] + ls2[t + 128] + ls2[t + 192];
            int slot = j & (SLOTS - 1);
            float* sb = sums + ((size_t)(b * SLOTS + slot) * 2) * 64;
            atomicAdd(&sb[t], s);
            atomicAdd(&sb[64 + t], s2);
        }
    }
}

// ---------------- Fused pool (BN finalize + BN+ReLU + mean) + head GEMM1 ----------------
__global__ __launch_bounds__(128) void pool_head_kernel(const unsigned short* __restrict__ x,
                                                        const float* __restrict__ sums,
                                                        const float* __restrict__ g0,
                                                        const float* __restrict__ g1,
                                                        const float* __restrict__ be0,
                                                        const float* __restrict__ be1,
                                                        const int* __restrict__ batch,
                                                        const float* __restrict__ Wf1,
                                                        float* __restrict__ T, int n) {
    __shared__ float row[128];
    const int g = blockIdx.x;
    const int c = threadIdx.x;      // 0..127
    const int b = c >> 6;
    const int ch = c & 63;
    float s0 = 0.f, s20 = 0.f;
#pragma unroll
    for (int k = 0; k < SLOTS; ++k) {
        const float* sb = sums + ((size_t)(b * SLOTS + k) * 2) * 64;
        s0 += sb[ch];
        s20 += sb[64 + ch];
    }
    const float invN = 1.0f / (float)NN;
    float mean = s0 * invN;
    float var = s20 * invN - mean * mean;
    float gamma = b ? g1[ch] : g0[ch];
    float beta = b ? be1[ch] : be0[ch];
    float sc = gamma * rsqrtf(var + 1e-5f);
    float sh = beta - mean * sc;

    // per-graph node range via binary search (batch sorted; broadcast-friendly)
    int lo = 0, hi = n;
    while (lo < hi) { int mid = (lo + hi) >> 1; if (batch[mid] < g) lo = mid + 1; else hi = mid; }
    const int start = lo;
    hi = n;
    while (lo < hi) { int mid = (lo + hi) >> 1; if (batch[mid] <= g) lo = mid + 1; else hi = mid; }
    const int end = lo;

    const unsigned short* xb = x + (size_t)b * NN * 64;
    float s = 0.f;
    for (int r = start; r < end; ++r)
        s += fmaxf(fmaf(bf2f(xb[(size_t)r * 64 + ch]), sc, sh), 0.f);
    float cf = (float)(end - start);
    row[c] = s / fmaxf(cf, 1.f);
    __syncthreads();

    if (c < 64) {
        float acc = 0.f;
#pragma unroll 8
        for (int k = 0; k < 128; ++k) acc = fmaf(row[k], Wf1[k * 64 + c], acc);
        T[(size_t)g * 64 + c] = acc;
    }
}

template<int C>
__global__ __launch_bounds__(256) void bn_stats_kernel(const float* __restrict__ x, int n,
                                                       float* __restrict__ sums) {
    constexpr int RP = 256 / C;
    __shared__ float ls[256], ls2[256];
    int c = threadIdx.x % C;
    int sub = threadIdx.x / C;
    float s = 0.f, s2 = 0.f;
    for (int r = blockIdx.x * RP + sub; r < n; r += gridDim.x * RP) {
        float v = x[(size_t)r * C + c];
        s += v; s2 += v * v;
    }
    ls[threadIdx.x] = s; ls2[threadIdx.x] = s2;
    __syncthreads();
    if (sub == 0) {
#pragma unroll
        for (int k = 1; k < RP; ++k) { s += ls[k * C + c]; s2 += ls2[k * C + c]; }
        atomicAdd(&sums[c], s);
        atomicAdd(&sums[C + c], s2);
    }
}

__global__ __launch_bounds__(64) void head_final_kernel(const float* __restrict__ T,
                                                        const float* __restrict__ hsums,
                                                        const float* __restrict__ gf1,
                                                        const float* __restrict__ bef1,
                                                        const float* __restrict__ Wf2,
                                                        const float* __restrict__ bf2,
                                                        float* __restrict__ out) {
    int g = blockIdx.x;
    int c = threadIdx.x;
    const float invG = 1.0f / (float)NG;
    float mean = hsums[c] * invG;
    float var = hsums[64 + c] * invG - mean * mean;
    float sc = gf1[c] * rsqrtf(var + 1e-5f);
    float sh = bef1[c] - mean * sc;
    float v = fmaxf(fmaf(T[(size_t)g * 64 + c], sc, sh), 0.f) * Wf2[c];
#pragma unroll
    for (int off = 32; off > 0; off >>= 1) v += __shfl_down(v, off, 64);
    if (c == 0) out[g] = v + bf2[0];
}

// ---------------- Host orchestration ----------------

static inline size_t alignup(size_t x) { return (x + 255) & ~(size_t)255; }

extern "C" void kernel_launch(void* const* d_in, const int* in_sizes, int n_in,
                              void* d_out, int out_size, void* d_ws, size_t ws_size,
                              hipStream_t stream) {
    const float* xc  = (const float*)d_in[0];
    const float* xs  = (const float*)d_in[1];
    const int*   eic = (const int*)d_in[2];
    const int*   eis = (const int*)d_in[3];
    const int*   batch = (const int*)d_in[4];
    const float* W1c = (const float*)d_in[5];
    const float* g1c = (const float*)d_in[7];
    const float* be1c = (const float*)d_in[8];
    const float* W2c = (const float*)d_in[9];
    const float* g2c = (const float*)d_in[11];
    const float* be2c = (const float*)d_in[12];
    const float* W1s = (const float*)d_in[13];
    const float* g1s = (const float*)d_in[15];
    const float* be1s = (const float*)d_in[16];
    const float* W2s = (const float*)d_in[17];
    const float* g2s = (const float*)d_in[19];
    const float* be2s = (const float*)d_in[20];
    const float* Wf1 = (const float*)d_in[21];
    const float* gf1 = (const float*)d_in[23];
    const float* bef1 = (const float*)d_in[24];
    const float* Wf2 = (const float*)d_in[25];
    const float* bf2 = (const float*)d_in[26];
    float* out = (float*)d_out;

    char* ws = (char*)d_ws;
    size_t off = 0;
    auto alloc = [&](size_t bytes) { char* p = ws + off; off += alignup(bytes); return p; };

    int*      bucketCnt = (int*)alloc(2 * NBUCK * 4);
    int*      bucketOff = (int*)alloc(2 * NBUCK * 4);
    int*      bucketCur = (int*)alloc(2 * NBUCK * 4);
    uint32_t* bent      = (uint32_t*)alloc((size_t)2 * NE * 4);   // reused as permw
    uint16_t* perm      = (uint16_t*)alloc(((size_t)2 * NE + 64) * 2);
    int*      row_ptr   = (int*)alloc(2 * (NN + 1) * 4);
    float*    dinv      = (float*)alloc((size_t)2 * NN * 4);
    unsigned short* xbf   = (unsigned short*)alloc((size_t)2 * NN * 64 * 2);
    unsigned short* aggbf = (unsigned short*)alloc((size_t)2 * NN * 64 * 2);
    unsigned short* h1bf  = (unsigned short*)alloc((size_t)2 * NN * 128 * 2);
    unsigned short* h2bf  = (unsigned short*)alloc((size_t)2 * NN * 64 * 2);
    unsigned short* Wp1   = (unsigned short*)alloc((size_t)2 * 64 * 128 * 2);
    unsigned short* Wp2   = (unsigned short*)alloc((size_t)2 * 128 * 64 * 2);
    float*    sums1     = (float*)alloc(((size_t)2 * SLOTS * 256 + (size_t)2 * SLOTS * 128 + 128) * 4);
    float*    sums2     = sums1 + (size_t)2 * SLOTS * 256;
    float*    hsums     = sums2 + (size_t)2 * SLOTS * 128;
    float*    T         = (float*)alloc((size_t)NG * 64 * 4);

    const int gemmBlocks = (NCHUNK + 3) / 4;   // 782
    const int aggBlocks = 12504;               // 2 nodes/wave, XCD-partitioned flat grid

    // ---- Fused preamble (conv + weight pack + stat/bucket zero) ----
    prep_kernel<<<PREP_TOT, 256, 0, stream>>>(xc, xs, xbf, W1c, W1s, Wp1,
                                              W2c, W2s, Wp2, sums1, bucketCnt);

    // ---- Bucketed CSR build ----
    bucket_hist<<<dim3(64, 2), 256, 0, stream>>>(eic + NE, eis + NE, bucketCnt, NE);
    bucket_scan<<<1, 64, 0, stream>>>(bucketCnt, bucketOff, bucketCur);
    bucket_scatter<<<dim3((NE + 2047) / 2048, 2), 256, 0, stream>>>(
        eic, eic + NE, eis, eis + NE, bucketCur, bent, NE);
    csr_build<<<dim3(NBUCK, 2), 256, 0, stream>>>(bent, bucketOff, bucketCnt,
                                                  row_ptr, dinv, perm);
    weight_fill<<<dim3((NE / 4 + 255) / 256, 2), 256, 0, stream>>>(perm, dinv, bent, NE);

    // ---- Layer 1: aggregate, MFMA GEMM 64->128 with fused BN stats ----
    agg2_kernel<false><<<aggBlocks, 256, 0, stream>>>(
        xbf, row_ptr, bent, dinv, aggbf, nullptr, NN);
    gemm1_mfma<<<dim3(gemmBlocks, 2), 256, 0, stream>>>(aggbf, Wp1, h1bf, sums1);

    // ---- Layer 2: MFMA GEMM 128->64 (BN finalize + BN+ReLU fused), then aggregate ----
    gemm2_mfma<<<dim3(gemmBlocks, 2), 256, 0, stream>>>(h1bf, Wp2, sums1,
                                                        g1c, g1s, be1c, be1s, h2bf);
    agg2_kernel<true><<<aggBlocks, 256, 0, stream>>>(
        h2bf, row_ptr, bent, dinv, aggbf, sums2, NN);

    // ---- Fused pool + head GEMM1 ----
    pool_head_kernel<<<NG, 128, 0, stream>>>(aggbf, sums2, g2c, g2s, be2c, be2s,
                                             batch, Wf1, T, NN);

    // ---- Head tail ----
    bn_stats_kernel<64><<<32, 256, 0, stream>>>(T, NG, hsums);
    head_final_kernel<<<NG, 64, 0, stream>>>(T, hsums, gf1, bef1, Wf2, bf2, out);
}

// Round 11
// 330.500 us; speedup vs baseline: 1.3821x; 1.3821x over previous
//
#include <hip/hip_runtime.h>
#include <hip/hip_bf16.h>
#include <cstdint>
#include <cstddef>

#define NN 50000
#define NE 600000
#define NG 2000
#define NBUCK 49          // ceil(50000 / 1024)
#define SLOTS 16
#define NCHUNK 3125       // 50000 / 16 exactly

typedef __attribute__((ext_vector_type(8))) short bf8;
typedef __attribute__((ext_vector_type(4))) float f32x4;

__device__ __forceinline__ unsigned short f2bf(float f) {
    uint32_t u = __float_as_uint(f);
    uint32_t r = (u + 0x7FFFu + ((u >> 16) & 1u)) >> 16;
    return (unsigned short)r;
}
__device__ __forceinline__ float bf2f(unsigned short h) {
    return __uint_as_float(((uint32_t)h) << 16);
}
__device__ __forceinline__ float lo16(uint32_t v) { return __uint_as_float(v << 16); }
__device__ __forceinline__ float hi16(uint32_t v) { return __uint_as_float(v & 0xFFFF0000u); }

// ---------------- Fused preamble: conv + pack_w x2 + stat/bucket zeroing ----------------
// Flat grid, block-range dispatch:
//   [0, 6250)        conv fp32->bf16 (2 graphs x 3125 blocks)
//   [6250, 6258)     pack W1 (64x128), 2 graphs x 4 blocks
//   [6258, 6266)     pack W2 (128x64), 2 graphs x 4 blocks
//   [6266, 6315)     zero sums1/sums2/hsums (12416 words)
//   6315             zero bucketCnt (98 ints)
#define PREP_CONV 6250
#define PREP_P1   6258
#define PREP_P2   6266
#define PREP_ZS   6315
#define PREP_TOT  6316

__device__ __forceinline__ void pack_w_body(const float* __restrict__ W,
                                            unsigned short* __restrict__ o,
                                            int idx, int K, int N) {
    const int total = (N / 16) * (K / 32) * 64;
    if (idx >= total) return;
    int l = idx & 63;
    int th = idx >> 6;
    int h = th % (K / 32);
    int t = th / (K / 32);
    int col = t * 16 + (l & 15);
    int k0 = h * 32 + (l >> 4) * 8;
    ushort4 lo = make_ushort4(f2bf(W[(k0 + 0) * N + col]), f2bf(W[(k0 + 1) * N + col]),
                              f2bf(W[(k0 + 2) * N + col]), f2bf(W[(k0 + 3) * N + col]));
    ushort4 hi = make_ushort4(f2bf(W[(k0 + 4) * N + col]), f2bf(W[(k0 + 5) * N + col]),
                              f2bf(W[(k0 + 6) * N + col]), f2bf(W[(k0 + 7) * N + col]));
    *(ushort4*)&o[idx * 8] = lo;
    *(ushort4*)&o[idx * 8 + 4] = hi;
}

__global__ __launch_bounds__(256) void prep_kernel(const float* __restrict__ x0,
                                                   const float* __restrict__ x1,
                                                   unsigned short* __restrict__ xbf,
                                                   const float* __restrict__ W1c,
                                                   const float* __restrict__ W1s,
                                                   unsigned short* __restrict__ Wp1,
                                                   const float* __restrict__ W2c,
                                                   const float* __restrict__ W2s,
                                                   unsigned short* __restrict__ Wp2,
                                                   float* __restrict__ sums,
                                                   int* __restrict__ bucketCnt) {
    const int bid = blockIdx.x;
    const int tid = threadIdx.x;
    if (bid < PREP_CONV) {
        const int b = bid >= 3125;
        const int lb = b ? bid - 3125 : bid;
        const float* x = b ? x1 : x0;
        unsigned short* o = xbf + (size_t)b * NN * 64;
        int i = (lb * 256 + tid) * 4;
        if (i + 3 < NN * 64) {
            float4 v = *(const float4*)&x[i];
            *(ushort4*)&o[i] = make_ushort4(f2bf(v.x), f2bf(v.y), f2bf(v.z), f2bf(v.w));
        }
    } else if (bid < PREP_P1) {
        const int local = bid - PREP_CONV;
        const int b = local >> 2;
        pack_w_body(b ? W1s : W1c, Wp1 + (size_t)b * 64 * 128,
                    (local & 3) * 256 + tid, 64, 128);
    } else if (bid < PREP_P2) {
        const int local = bid - PREP_P1;
        const int b = local >> 2;
        pack_w_body(b ? W2s : W2c, Wp2 + (size_t)b * 128 * 64,
                    (local & 3) * 256 + tid, 128, 64);
    } else if (bid < PREP_ZS) {
        int i = (bid - PREP_P2) * 256 + tid;
        if (i < 12416) sums[i] = 0.f;
    } else {
        if (tid < 2 * NBUCK) bucketCnt[tid] = 0;
    }
}

// ---------------- Bucketed CSR build ----------------
__global__ __launch_bounds__(256) void bucket_hist(const int* __restrict__ d0,
                                                   const int* __restrict__ d1,
                                                   int* __restrict__ bucketCnt, int nE) {
    int b = blockIdx.y;
    const int* dst = b ? d1 : d0;
    __shared__ int h[NBUCK];
    for (int i = threadIdx.x; i < NBUCK; i += 256) h[i] = 0;
    __syncthreads();
    for (int e = blockIdx.x * 256 + threadIdx.x; e < nE; e += gridDim.x * 256)
        atomicAdd(&h[dst[e] >> 10], 1);
    __syncthreads();
    for (int i = threadIdx.x; i < NBUCK; i += 256)
        if (h[i]) atomicAdd(&bucketCnt[b * NBUCK + i], h[i]);
}

__global__ void bucket_scan(const int* __restrict__ bucketCnt,
                            int* __restrict__ bucketOff, int* __restrict__ bucketCur) {
    int b = threadIdx.x;
    if (b < 2) {
        int run = 0;
        for (int i = 0; i < NBUCK; ++i) {
            bucketOff[b * NBUCK + i] = run;
            bucketCur[b * NBUCK + i] = run;
            run += bucketCnt[b * NBUCK + i];
        }
    }
}

__global__ __launch_bounds__(256) void bucket_scatter(const int* __restrict__ s0,
                                                      const int* __restrict__ d0,
                                                      const int* __restrict__ s1,
                                                      const int* __restrict__ d1,
                                                      int* __restrict__ bucketCur,
                                                      uint32_t* __restrict__ bent, int nE) {
    int b = blockIdx.y;
    const int* src = b ? s1 : s0;
    const int* dst = b ? d1 : d0;
    __shared__ int cnt[NBUCK];
    __shared__ int base[NBUCK];
    const int tid = threadIdx.x;
    for (int i = tid; i < NBUCK; i += 256) cnt[i] = 0;
    __syncthreads();

    const int e0 = blockIdx.x * 2048 + tid;
    int bk[8], slot[8];
    uint32_t pay[8];
#pragma unroll
    for (int k = 0; k < 8; ++k) {
        int e = e0 + k * 256;
        if (e < nE) {
            int d = dst[e], s = src[e];
            bk[k] = d >> 10;
            pay[k] = ((uint32_t)(d & 1023) << 16) | (uint32_t)s;
            slot[k] = atomicAdd(&cnt[bk[k]], 1);
        } else bk[k] = -1;
    }
    __syncthreads();
    for (int i = tid; i < NBUCK; i += 256) {
        int c = cnt[i];
        base[i] = c ? atomicAdd(&bucketCur[b * NBUCK + i], c) : 0;
    }
    __syncthreads();
#pragma unroll
    for (int k = 0; k < 8; ++k)
        if (bk[k] >= 0)
            bent[(size_t)b * NE + base[bk[k]] + slot[k]] = pay[k];
}

__global__ __launch_bounds__(256) void csr_build(const uint32_t* __restrict__ bent,
                                                 const int* __restrict__ bucketOff,
                                                 const int* __restrict__ bucketCnt,
                                                 int* __restrict__ row_ptr,
                                                 float* __restrict__ dinv,
                                                 uint16_t* __restrict__ perm) {
    __shared__ int lcnt[1024];
    __shared__ int lcur[1024];
    __shared__ int sscan[256];
    const int bk = blockIdx.x;
    const int b = blockIdx.y;
    const int tid = threadIdx.x;
    const int ebase = bucketOff[b * NBUCK + bk];
    const int ecnt = bucketCnt[b * NBUCK + bk];
    const int node0 = bk << 10;
    const uint32_t* be = bent + (size_t)b * NE + ebase;
    int* rp = row_ptr + b * (NN + 1);
    float* dv = dinv + (size_t)b * NN;
    uint16_t* pm = perm + (size_t)b * NE + ebase;

    for (int i = tid; i < 1024; i += 256) lcnt[i] = 0;
    __syncthreads();
    for (int i = tid; i < ecnt; i += 256) atomicAdd(&lcnt[be[i] >> 16], 1);
    __syncthreads();

    int c[4], s = 0;
#pragma unroll
    for (int j = 0; j < 4; ++j) { c[j] = lcnt[tid * 4 + j]; s += c[j]; }
    sscan[tid] = s;
    __syncthreads();
    for (int off = 1; off < 256; off <<= 1) {
        int v = (tid >= off) ? sscan[tid - off] : 0;
        __syncthreads();
        sscan[tid] += v;
        __syncthreads();
    }
    int run = sscan[tid] - s;
#pragma unroll
    for (int j = 0; j < 4; ++j) {
        int nl = tid * 4 + j;
        int g = node0 + nl;
        if (g < NN) {
            rp[g] = ebase + run;
            lcur[nl] = run;
            dv[g] = rsqrtf((float)c[j] + 1.0f);
        }
        run += c[j];
    }
    if (bk == NBUCK - 1 && tid == 0) rp[NN] = ebase + ecnt;
    __syncthreads();

    for (int i = tid; i < ecnt; i += 256) {
        uint32_t en = be[i];
        int nl = en >> 16;
        int pos = atomicAdd(&lcur[nl], 1);
        pm[pos] = (uint16_t)(en & 0xFFFFu);
    }
}

__global__ __launch_bounds__(256) void weight_fill(const uint16_t* __restrict__ perm,
                                                   const float* __restrict__ dinv,
                                                   uint32_t* __restrict__ permw, int nE) {
    int b = blockIdx.y;
    const uint16_t* pm = perm + (size_t)b * NE;
    const float* dv = dinv + (size_t)b * NN;
    uint32_t* pw = permw + (size_t)b * NE;
    int i = (blockIdx.x * 256 + threadIdx.x) * 4;
    if (i + 3 < nE) {
        ushort4 s4 = *(const ushort4*)&pm[i];
        uint4 o;
        o.x = ((uint32_t)f2bf(dv[s4.x]) << 16) | (uint32_t)s4.x;
        o.y = ((uint32_t)f2bf(dv[s4.y]) << 16) | (uint32_t)s4.y;
        o.z = ((uint32_t)f2bf(dv[s4.z]) << 16) | (uint32_t)s4.z;
        o.w = ((uint32_t)f2bf(dv[s4.w]) << 16) | (uint32_t)s4.w;
        *(uint4*)&pw[i] = o;
    } else {
        for (; i < nE; ++i) {
            uint16_t s = pm[i];
            pw[i] = ((uint32_t)f2bf(dv[s]) << 16) | (uint32_t)s;
        }
    }
}

// ---------------- GEMM1 (MFMA, swapped operands): Y[n,128] = X[n,64] @ W[64,128] ----------------
// Pure GEMM; BN1 stats done by stats128_bf16 (LDS-atomic fusion measured 13x slower).
__global__ __launch_bounds__(256) void gemm1_mfma(const unsigned short* __restrict__ Xbf,
                                                  const unsigned short* __restrict__ Wp,
                                                  unsigned short* __restrict__ Y) {
    const int b = blockIdx.y;
    const unsigned short* __restrict__ X = Xbf + (size_t)b * NN * 64;
    const unsigned short* __restrict__ W = Wp + (size_t)b * 64 * 128;
    unsigned short* __restrict__ Yb = Y + (size_t)b * NN * 128;
    const int tid = threadIdx.x;
    const int w = tid >> 6, lane = tid & 63;
    const int chunk = blockIdx.x * 4 + w;
    if (chunk >= NCHUNK) return;
    const int m = lane & 15, quad = lane >> 4;

    const int row = chunk * 16 + m;
    bf8 a0 = *(const bf8*)&X[(size_t)row * 64 + quad * 8];
    bf8 a1 = *(const bf8*)&X[(size_t)row * 64 + 32 + quad * 8];
    f32x4 acc[8];
#pragma unroll
    for (int t = 0; t < 8; ++t) acc[t] = (f32x4){0.f, 0.f, 0.f, 0.f};
#pragma unroll
    for (int t = 0; t < 8; ++t) {
        bf8 b0 = *(const bf8*)&W[((t * 2 + 0) * 64 + lane) * 8];
        bf8 b1 = *(const bf8*)&W[((t * 2 + 1) * 64 + lane) * 8];
        acc[t] = __builtin_amdgcn_mfma_f32_16x16x32_bf16(b0, a0, acc[t], 0, 0, 0);
        acc[t] = __builtin_amdgcn_mfma_f32_16x16x32_bf16(b1, a1, acc[t], 0, 0, 0);
    }
#pragma unroll
    for (int t = 0; t < 8; ++t) {
        uint32_t lo = (uint32_t)f2bf(acc[t][0]) | ((uint32_t)f2bf(acc[t][1]) << 16);
        uint32_t hi = (uint32_t)f2bf(acc[t][2]) | ((uint32_t)f2bf(acc[t][3]) << 16);
        *(uint2*)&Yb[(size_t)row * 128 + t * 16 + quad * 4] = make_uint2(lo, hi);
    }
}

// ---------------- BN stats over bf16 [NN,128] (vectorized, slot-striped output) ----------------
__global__ __launch_bounds__(256) void stats128_bf16(const unsigned short* __restrict__ Y,
                                                     float* __restrict__ sums) {
    const int b = blockIdx.y;
    const unsigned short* __restrict__ Yb = Y + (size_t)b * NN * 128;
    const int g = threadIdx.x & 31;    // 4-channel group
    const int rs = threadIdx.x >> 5;   // 0..7 row sub-stripe
    float s0 = 0.f, s1 = 0.f, s2 = 0.f, s3 = 0.f;
    float q0 = 0.f, q1 = 0.f, q2 = 0.f, q3 = 0.f;
    for (int r = blockIdx.x * 8 + rs; r < NN; r += gridDim.x * 8) {
        uint2 v = *(const uint2*)&Yb[(size_t)r * 128 + g * 4];
        float x0 = lo16(v.x);
        float x1 = hi16(v.x);
        float x2 = lo16(v.y);
        float x3 = hi16(v.y);
        s0 += x0; s1 += x1; s2 += x2; s3 += x3;
        q0 = fmaf(x0, x0, q0); q1 = fmaf(x1, x1, q1);
        q2 = fmaf(x2, x2, q2); q3 = fmaf(x3, x3, q3);
    }
    __shared__ float ls[8][128], lq[8][128];
    *(float4*)&ls[rs][g * 4] = make_float4(s0, s1, s2, s3);
    *(float4*)&lq[rs][g * 4] = make_float4(q0, q1, q2, q3);
    __syncthreads();
    if (threadIdx.x < 128) {
        const int c = threadIdx.x;
        float S = 0.f, Q = 0.f;
#pragma unroll
        for (int k = 0; k < 8; ++k) { S += ls[k][c]; Q += lq[k][c]; }
        int slot = blockIdx.x & (SLOTS - 1);
        float* sb = sums + (size_t)(b * SLOTS + slot) * 256;
        atomicAdd(&sb[c], S);
        atomicAdd(&sb[128 + c], Q);
    }
}

// ---------------- GEMM2 (MFMA, swapped operands, fused BN-finalize prologue) ----------------
__global__ __launch_bounds__(256) void gemm2_mfma(const unsigned short* __restrict__ H1,
                                                  const unsigned short* __restrict__ Wp,
                                                  const float* __restrict__ sums,
                                                  const float* __restrict__ g0,
                                                  const float* __restrict__ g1,
                                                  const float* __restrict__ be0,
                                                  const float* __restrict__ be1,
                                                  unsigned short* __restrict__ Y) {
    __shared__ float scLds[128], shLds[128];
    const int b = blockIdx.y;
    const unsigned short* __restrict__ X = H1 + (size_t)b * NN * 128;
    const unsigned short* __restrict__ W = Wp + (size_t)b * 128 * 64;
    unsigned short* __restrict__ Yb = Y + (size_t)b * NN * 64;
    const int tid = threadIdx.x;

    if (tid < 128) {
        float s = 0.f, s2 = 0.f;
#pragma unroll
        for (int k = 0; k < SLOTS; ++k) {
            const float* sb = sums + (size_t)(b * SLOTS + k) * 256;
            s += sb[tid];
            s2 += sb[128 + tid];
        }
        const float invN = 1.0f / (float)NN;
        float mean = s * invN;
        float var = s2 * invN - mean * mean;
        float gamma = b ? g1[tid] : g0[tid];
        float beta = b ? be1[tid] : be0[tid];
        float sc = gamma * rsqrtf(var + 1e-5f);
        scLds[tid] = sc;
        shLds[tid] = beta - mean * sc;
    }
    __syncthreads();

    const int w = tid >> 6, lane = tid & 63;
    const int chunk = blockIdx.x * 4 + w;
    if (chunk >= NCHUNK) return;
    const int m = lane & 15, quad = lane >> 4;
    const int row = chunk * 16 + m;

    f32x4 acc[4];
#pragma unroll
    for (int t = 0; t < 4; ++t) acc[t] = (f32x4){0.f, 0.f, 0.f, 0.f};
#pragma unroll
    for (int h = 0; h < 4; ++h) {
        const int k0 = h * 32 + quad * 8;
        bf8 araw = *(const bf8*)&X[(size_t)row * 128 + k0];
        float4 sc0 = *(const float4*)&scLds[k0];
        float4 sc1 = *(const float4*)&scLds[k0 + 4];
        float4 sh0 = *(const float4*)&shLds[k0];
        float4 sh1 = *(const float4*)&shLds[k0 + 4];
        float scv[8] = {sc0.x, sc0.y, sc0.z, sc0.w, sc1.x, sc1.y, sc1.z, sc1.w};
        float shv[8] = {sh0.x, sh0.y, sh0.z, sh0.w, sh1.x, sh1.y, sh1.z, sh1.w};
        bf8 af;
#pragma unroll
        for (int j = 0; j < 8; ++j) {
            float v = bf2f((unsigned short)araw[j]);
            v = fmaxf(fmaf(v, scv[j], shv[j]), 0.f);
            af[j] = (short)f2bf(v);
        }
#pragma unroll
        for (int t = 0; t < 4; ++t) {
            bf8 bf = *(const bf8*)&W[((t * 4 + h) * 64 + lane) * 8];
            acc[t] = __builtin_amdgcn_mfma_f32_16x16x32_bf16(bf, af, acc[t], 0, 0, 0);
        }
    }
#pragma unroll
    for (int t = 0; t < 4; ++t) {
        uint32_t lo = (uint32_t)f2bf(acc[t][0]) | ((uint32_t)f2bf(acc[t][1]) << 16);
        uint32_t hi = (uint32_t)f2bf(acc[t][2]) | ((uint32_t)f2bf(acc[t][3]) << 16);
        *(uint2*)&Yb[(size_t)row * 64 + t * 16 + quad * 4] = make_uint2(lo, hi);
    }
}

// ---------------- Batched aggregation: 2 nodes per wave, XCD-partitioned grid ----------------
template<bool STATS>
__global__ __launch_bounds__(256) void agg2_kernel(const unsigned short* __restrict__ hall,
                                                   const int* __restrict__ row_ptr,
                                                   const uint32_t* __restrict__ permw,
                                                   const float* __restrict__ dinv,
                                                   unsigned short* __restrict__ out,
                                                   float* __restrict__ sums, int nNodes) {
    const int bid = blockIdx.x;
    const int xcd = bid & 7;
    const int b = xcd >> 2;                      // graph = XCD group
    const int j = (bid >> 3) * 4 + (xcd & 3);    // block index within graph
    const unsigned short* __restrict__ h = hall + (size_t)b * NN * 64;
    const int* rp = row_ptr + b * (NN + 1);
    const uint32_t* pe = permw + (size_t)b * NE;
    const float* dv = dinv + (size_t)b * NN;
    unsigned short* ob = out + (size_t)b * nNodes * 64;

    const int w = threadIdx.x >> 6;
    const int lane = threadIdx.x & 63;
    const int q = lane & 15;        // channel quad: channels q*4 .. q*4+3
    const int r = lane >> 4;        // edge sub-slot 0..3 within each batch step
    const int d0 = j * 8 + w * 2;
    const int d1 = d0 + 1;
    const bool actA = d0 < nNodes;
    const bool actB = d1 < nNodes;

    float fA0 = 0.f, fA1 = 0.f, fA2 = 0.f, fA3 = 0.f;
    float fB0 = 0.f, fB1 = 0.f, fB2 = 0.f, fB3 = 0.f;
    int p0a = 0, p1a = 0, p0b = 0, p1b = 0;
    float dia = 0.f, dib = 0.f;
    if (actA) { p0a = rp[d0]; p1a = rp[d0 + 1]; dia = dv[d0]; }
    if (actB) { p0b = rp[d1]; p1b = rp[d1 + 1]; dib = dv[d1]; }

    float aA0 = 0.f, aA1 = 0.f, aA2 = 0.f, aA3 = 0.f;
    float aB0 = 0.f, aB1 = 0.f, aB2 = 0.f, aB3 = 0.f;
    int pa = p0a, pb = p0b;
    while (pa < p1a || pb < p1b) {
        uint32_t enA[4], enB[4];
#pragma unroll
        for (int k = 0; k < 4; ++k) {
            int e = pa + k * 4 + r;
            bool vld = e < p1a;
            enA[k] = pe[vld ? e : p0a];
            if (!vld) enA[k] &= 0xFFFFu;          // zero weight, warm row idx
        }
#pragma unroll
        for (int k = 0; k < 4; ++k) {
            int e = pb + k * 4 + r;
            bool vld = e < p1b;
            enB[k] = pe[vld ? e : p0b];
            if (!vld) enB[k] &= 0xFFFFu;
        }
#pragma unroll
        for (int k = 0; k < 4; ++k) {
            const int idx = (int)(enA[k] & 0xFFFFu);
            const float wk = __uint_as_float(enA[k] & 0xFFFF0000u);
            const uint2 hv = *(const uint2*)&h[(size_t)idx * 64 + q * 4];
            aA0 = fmaf(wk, lo16(hv.x), aA0);
            aA1 = fmaf(wk, hi16(hv.x), aA1);
            aA2 = fmaf(wk, lo16(hv.y), aA2);
            aA3 = fmaf(wk, hi16(hv.y), aA3);
        }
#pragma unroll
        for (int k = 0; k < 4; ++k) {
            const int idx = (int)(enB[k] & 0xFFFFu);
            const float wk = __uint_as_float(enB[k] & 0xFFFF0000u);
            const uint2 hv = *(const uint2*)&h[(size_t)idx * 64 + q * 4];
            aB0 = fmaf(wk, lo16(hv.x), aB0);
            aB1 = fmaf(wk, hi16(hv.x), aB1);
            aB2 = fmaf(wk, lo16(hv.y), aB2);
            aB3 = fmaf(wk, hi16(hv.y), aB3);
        }
        pa += 16;
        pb += 16;
    }
    aA0 += __shfl_xor(aA0, 16, 64); aA0 += __shfl_xor(aA0, 32, 64);
    aA1 += __shfl_xor(aA1, 16, 64); aA1 += __shfl_xor(aA1, 32, 64);
    aA2 += __shfl_xor(aA2, 16, 64); aA2 += __shfl_xor(aA2, 32, 64);
    aA3 += __shfl_xor(aA3, 16, 64); aA3 += __shfl_xor(aA3, 32, 64);
    aB0 += __shfl_xor(aB0, 16, 64); aB0 += __shfl_xor(aB0, 32, 64);
    aB1 += __shfl_xor(aB1, 16, 64); aB1 += __shfl_xor(aB1, 32, 64);
    aB2 += __shfl_xor(aB2, 16, 64); aB2 += __shfl_xor(aB2, 32, 64);
    aB3 += __shfl_xor(aB3, 16, 64); aB3 += __shfl_xor(aB3, 32, 64);

    if (actA) {
        const uint2 sv = *(const uint2*)&h[(size_t)d0 * 64 + q * 4];
        fA0 = dia * fmaf(dia, lo16(sv.x), aA0);
        fA1 = dia * fmaf(dia, hi16(sv.x), aA1);
        fA2 = dia * fmaf(dia, lo16(sv.y), aA2);
        fA3 = dia * fmaf(dia, hi16(sv.y), aA3);
        if (r == 0) {
            uint32_t o0 = (uint32_t)f2bf(fA0) | ((uint32_t)f2bf(fA1) << 16);
            uint32_t o1 = (uint32_t)f2bf(fA2) | ((uint32_t)f2bf(fA3) << 16);
            *(uint2*)&ob[(size_t)d0 * 64 + q * 4] = make_uint2(o0, o1);
        }
    }
    if (actB) {
        const uint2 sv = *(const uint2*)&h[(size_t)d1 * 64 + q * 4];
        fB0 = dib * fmaf(dib, lo16(sv.x), aB0);
        fB1 = dib * fmaf(dib, hi16(sv.x), aB1);
        fB2 = dib * fmaf(dib, lo16(sv.y), aB2);
        fB3 = dib * fmaf(dib, hi16(sv.y), aB3);
        if (r == 0) {
            uint32_t o0 = (uint32_t)f2bf(fB0) | ((uint32_t)f2bf(fB1) << 16);
            uint32_t o1 = (uint32_t)f2bf(fB2) | ((uint32_t)f2bf(fB3) << 16);
            *(uint2*)&ob[(size_t)d1 * 64 + q * 4] = make_uint2(o0, o1);
        }
    }
    if constexpr (STATS) {
        __shared__ float ls[256], ls2[256];
        if (lane < 16) {
            *(float4*)&ls[w * 64 + q * 4] =
                make_float4(fA0 + fB0, fA1 + fB1, fA2 + fB2, fA3 + fB3);
            *(float4*)&ls2[w * 64 + q * 4] =
                make_float4(fA0 * fA0 + fB0 * fB0, fA1 * fA1 + fB1 * fB1,
                            fA2 * fA2 + fB2 * fB2, fA3 * fA3 + fB3 * fB3);
        }
        __syncthreads();
        if (threadIdx.x < 64) {
            const int t = threadIdx.x;
            float s  = ls[t]  + ls[t + 64]  + ls[t + 128]  + ls[t + 192];
            float s2 = ls2[t] + ls2[t + 64] + ls2[t + 128] + ls2[t + 192];
            int slot = j & (SLOTS - 1);
            float* sb = sums + ((size_t)(b * SLOTS + slot) * 2) * 64;
            atomicAdd(&sb[t], s);
            atomicAdd(&sb[64 + t], s2);
        }
    }
}

// ---------------- Fused pool (BN finalize + BN+ReLU + mean) + head GEMM1 ----------------
__global__ __launch_bounds__(128) void pool_head_kernel(const unsigned short* __restrict__ x,
                                                        const float* __restrict__ sums,
                                                        const float* __restrict__ g0,
                                                        const float* __restrict__ g1,
                                                        const float* __restrict__ be0,
                                                        const float* __restrict__ be1,
                                                        const int* __restrict__ batch,
                                                        const float* __restrict__ Wf1,
                                                        float* __restrict__ T, int n) {
    __shared__ float row[128];
    const int g = blockIdx.x;
    const int c = threadIdx.x;      // 0..127
    const int b = c >> 6;
    const int ch = c & 63;
    float s0 = 0.f, s20 = 0.f;
#pragma unroll
    for (int k = 0; k < SLOTS; ++k) {
        const float* sb = sums + ((size_t)(b * SLOTS + k) * 2) * 64;
        s0 += sb[ch];
        s20 += sb[64 + ch];
    }
    const float invN = 1.0f / (float)NN;
    float mean = s0 * invN;
    float var = s20 * invN - mean * mean;
    float gamma = b ? g1[ch] : g0[ch];
    float beta = b ? be1[ch] : be0[ch];
    float sc = gamma * rsqrtf(var + 1e-5f);
    float sh = beta - mean * sc;

    int lo = 0, hi = n;
    while (lo < hi) { int mid = (lo + hi) >> 1; if (batch[mid] < g) lo = mid + 1; else hi = mid; }
    const int start = lo;
    hi = n;
    while (lo < hi) { int mid = (lo + hi) >> 1; if (batch[mid] <= g) lo = mid + 1; else hi = mid; }
    const int end = lo;

    const unsigned short* xb = x + (size_t)b * NN * 64;
    float s = 0.f;
    for (int r = start; r < end; ++r)
        s += fmaxf(fmaf(bf2f(xb[(size_t)r * 64 + ch]), sc, sh), 0.f);
    float cf = (float)(end - start);
    row[c] = s / fmaxf(cf, 1.f);
    __syncthreads();

    if (c < 64) {
        float acc = 0.f;
#pragma unroll 8
        for (int k = 0; k < 128; ++k) acc = fmaf(row[k], Wf1[k * 64 + c], acc);
        T[(size_t)g * 64 + c] = acc;
    }
}

template<int C>
__global__ __launch_bounds__(256) void bn_stats_kernel(const float* __restrict__ x, int n,
                                                       float* __restrict__ sums) {
    constexpr int RP = 256 / C;
    __shared__ float ls[256], ls2[256];
    int c = threadIdx.x % C;
    int sub = threadIdx.x / C;
    float s = 0.f, s2 = 0.f;
    for (int r = blockIdx.x * RP + sub; r < n; r += gridDim.x * RP) {
        float v = x[(size_t)r * C + c];
        s += v; s2 += v * v;
    }
    ls[threadIdx.x] = s; ls2[threadIdx.x] = s2;
    __syncthreads();
    if (sub == 0) {
#pragma unroll
        for (int k = 1; k < RP; ++k) { s += ls[k * C + c]; s2 += ls2[k * C + c]; }
        atomicAdd(&sums[c], s);
        atomicAdd(&sums[C + c], s2);
    }
}

__global__ __launch_bounds__(64) void head_final_kernel(const float* __restrict__ T,
                                                        const float* __restrict__ hsums,
                                                        const float* __restrict__ gf1,
                                                        const float* __restrict__ bef1,
                                                        const float* __restrict__ Wf2,
                                                        const float* __restrict__ bf2,
                                                        float* __restrict__ out) {
    int g = blockIdx.x;
    int c = threadIdx.x;
    const float invG = 1.0f / (float)NG;
    float mean = hsums[c] * invG;
    float var = hsums[64 + c] * invG - mean * mean;
    float sc = gf1[c] * rsqrtf(var + 1e-5f);
    float sh = bef1[c] - mean * sc;
    float v = fmaxf(fmaf(T[(size_t)g * 64 + c], sc, sh), 0.f) * Wf2[c];
#pragma unroll
    for (int off = 32; off > 0; off >>= 1) v += __shfl_down(v, off, 64);
    if (c == 0) out[g] = v + bf2[0];
}

// ---------------- Host orchestration ----------------

static inline size_t alignup(size_t x) { return (x + 255) & ~(size_t)255; }

extern "C" void kernel_launch(void* const* d_in, const int* in_sizes, int n_in,
                              void* d_out, int out_size, void* d_ws, size_t ws_size,
                              hipStream_t stream) {
    const float* xc  = (const float*)d_in[0];
    const float* xs  = (const float*)d_in[1];
    const int*   eic = (const int*)d_in[2];
    const int*   eis = (const int*)d_in[3];
    const int*   batch = (const int*)d_in[4];
    const float* W1c = (const float*)d_in[5];
    const float* g1c = (const float*)d_in[7];
    const float* be1c = (const float*)d_in[8];
    const float* W2c = (const float*)d_in[9];
    const float* g2c = (const float*)d_in[11];
    const float* be2c = (const float*)d_in[12];
    const float* W1s = (const float*)d_in[13];
    const float* g1s = (const float*)d_in[15];
    const float* be1s = (const float*)d_in[16];
    const float* W2s = (const float*)d_in[17];
    const float* g2s = (const float*)d_in[19];
    const float* be2s = (const float*)d_in[20];
    const float* Wf1 = (const float*)d_in[21];
    const float* gf1 = (const float*)d_in[23];
    const float* bef1 = (const float*)d_in[24];
    const float* Wf2 = (const float*)d_in[25];
    const float* bf2 = (const float*)d_in[26];
    float* out = (float*)d_out;

    char* ws = (char*)d_ws;
    size_t off = 0;
    auto alloc = [&](size_t bytes) { char* p = ws + off; off += alignup(bytes); return p; };

    int*      bucketCnt = (int*)alloc(2 * NBUCK * 4);
    int*      bucketOff = (int*)alloc(2 * NBUCK * 4);
    int*      bucketCur = (int*)alloc(2 * NBUCK * 4);
    uint32_t* bent      = (uint32_t*)alloc((size_t)2 * NE * 4);   // reused as permw
    uint16_t* perm      = (uint16_t*)alloc(((size_t)2 * NE + 64) * 2);
    int*      row_ptr   = (int*)alloc(2 * (NN + 1) * 4);
    float*    dinv      = (float*)alloc((size_t)2 * NN * 4);
    unsigned short* xbf   = (unsigned short*)alloc((size_t)2 * NN * 64 * 2);
    unsigned short* aggbf = (unsigned short*)alloc((size_t)2 * NN * 64 * 2);
    unsigned short* h1bf  = (unsigned short*)alloc((size_t)2 * NN * 128 * 2);
    unsigned short* h2bf  = (unsigned short*)alloc((size_t)2 * NN * 64 * 2);
    unsigned short* Wp1   = (unsigned short*)alloc((size_t)2 * 64 * 128 * 2);
    unsigned short* Wp2   = (unsigned short*)alloc((size_t)2 * 128 * 64 * 2);
    float*    sums1     = (float*)alloc(((size_t)2 * SLOTS * 256 + (size_t)2 * SLOTS * 128 + 128) * 4);
    float*    sums2     = sums1 + (size_t)2 * SLOTS * 256;
    float*    hsums     = sums2 + (size_t)2 * SLOTS * 128;
    float*    T         = (float*)alloc((size_t)NG * 64 * 4);

    const int gemmBlocks = (NCHUNK + 3) / 4;   // 782
    const int aggBlocks = 12504;               // 2 nodes/wave, XCD-partitioned flat grid

    // ---- Fused preamble (conv + weight pack + stat/bucket zero) ----
    prep_kernel<<<PREP_TOT, 256, 0, stream>>>(xc, xs, xbf, W1c, W1s, Wp1,
                                              W2c, W2s, Wp2, sums1, bucketCnt);

    // ---- Bucketed CSR build ----
    bucket_hist<<<dim3(64, 2), 256, 0, stream>>>(eic + NE, eis + NE, bucketCnt, NE);
    bucket_scan<<<1, 64, 0, stream>>>(bucketCnt, bucketOff, bucketCur);
    bucket_scatter<<<dim3((NE + 2047) / 2048, 2), 256, 0, stream>>>(
        eic, eic + NE, eis, eis + NE, bucketCur, bent, NE);
    csr_build<<<dim3(NBUCK, 2), 256, 0, stream>>>(bent, bucketOff, bucketCnt,
                                                  row_ptr, dinv, perm);
    weight_fill<<<dim3((NE / 4 + 255) / 256, 2), 256, 0, stream>>>(perm, dinv, bent, NE);

    // ---- Layer 1: aggregate, MFMA GEMM 64->128, standalone BN stats ----
    agg2_kernel<false><<<aggBlocks, 256, 0, stream>>>(
        xbf, row_ptr, bent, dinv, aggbf, nullptr, NN);
    gemm1_mfma<<<dim3(gemmBlocks, 2), 256, 0, stream>>>(aggbf, Wp1, h1bf);
    stats128_bf16<<<dim3(256, 2), 256, 0, stream>>>(h1bf, sums1);

    // ---- Layer 2: MFMA GEMM 128->64 (BN finalize + BN+ReLU fused), then aggregate ----
    gemm2_mfma<<<dim3(gemmBlocks, 2), 256, 0, stream>>>(h1bf, Wp2, sums1,
                                                        g1c, g1s, be1c, be1s, h2bf);
    agg2_kernel<true><<<aggBlocks, 256, 0, stream>>>(
        h2bf, row_ptr, bent, dinv, aggbf, sums2, NN);

    // ---- Fused pool + head GEMM1 ----
    pool_head_kernel<<<NG, 128, 0, stream>>>(aggbf, sums2, g2c, g2s, be2c, be2s,
                                             batch, Wf1, T, NN);

    // ---- Head tail ----
    bn_stats_kernel<64><<<32, 256, 0, stream>>>(T, NG, hsums);
    head_final_kernel<<<NG, 64, 0, stream>>>(T, hsums, gf1, bef1, Wf2, bf2, out);
}